// Round 2
// baseline (205.991 us; speedup 1.0000x reference)
//
#include <hip/hip_runtime.h>

typedef unsigned int u32;
typedef unsigned long long u64;
typedef __bf16 bf16x8 __attribute__((ext_vector_type(8)));
typedef float f32x4 __attribute__((ext_vector_type(4)));

#define N_TOK 4096   // B*S
#define IN_DIM 2048
#define OUT_DIM 4096
#define NCB 128      // codebooks C
#define NCENT 16     // centroids K
#define VLEN 16      // vec_len V
#define CK 2048      // NCB*NCENT  (GEMM inner dim)
#define KB 64        // K-blocks (CK/32)

static __device__ __forceinline__ unsigned short f2bf(float f) {
  u32 u = __float_as_uint(f);
  u = (u + 0x7FFFu + ((u >> 16) & 1u)) >> 16;  // round-to-nearest-even
  return (unsigned short)u;
}

// ---------------------------------------------------------------------------
// k_prep: lut-build (blocks 0..1023) || Chebyshev argmin (blocks 1024..2047)
// in ONE dispatch so the two independent producers overlap (sum -> max).
//
// argmin part (rewritten): block = 32 tokens x 16 codebooks (one 256-col
// chunk). 2 tokens/thread halves centroid LDS re-reads; centroids read as
// explicit float4 (ds_read_b128, 2-way bank alias only); x goes global->reg
// directly (no LDS staging, no extra barriers). 1024 blocks -> 4 blocks/CU.
// fp32 sub/abs/max, strict < ascending k == np.argmin tie-break (unchanged).
// ---------------------------------------------------------------------------
__global__ __launch_bounds__(256) void k_prep(
    const float* __restrict__ x,
    const float* __restrict__ w,
    const float* __restrict__ cents,
    unsigned char* __restrict__ idx,
    char* __restrict__ lutF) {
  __shared__ float cs[16 * 260];  // 16.6KB (argmin path only)
  const int tid = threadIdx.x;
  const int b = blockIdx.x;

  if (b < 1024) {
    // ---- LUT path (same math as the passing k_lut) ----
    const int o0 = (b & 63) * 64;
    const int cg = b >> 6;  // 8-codebook group 0..15
    const int p = tid >> 6;
    const int ol = tid & 63;
    const int o = o0 + ol;

    float acc[2][16];
#pragma unroll
    for (int cc = 0; cc < 2; ++cc)
#pragma unroll
      for (int k = 0; k < 16; ++k) acc[cc][k] = 0.f;

#pragma unroll
    for (int cc = 0; cc < 2; ++cc) {
      const int c = __builtin_amdgcn_readfirstlane(cg * 8 + p * 2 + cc);
      const float* cb = cents + (size_t)c * (NCENT * VLEN);  // scalar loads
#pragma unroll
      for (int v = 0; v < VLEN; ++v) {
        const float wv = w[(size_t)(c * 16 + v) * OUT_DIM + o];
#pragma unroll
        for (int k = 0; k < 16; ++k) acc[cc][k] = fmaf(cb[k * 16 + v], wv, acc[cc][k]);
      }
    }

#pragma unroll
    for (int cc = 0; cc < 2; ++cc) {
      const int c = cg * 8 + p * 2 + cc;
      u32 g[8];
#pragma unroll
      for (int kk = 0; kk < 8; ++kk)
        g[kk] = (u32)f2bf(acc[cc][2 * kk]) | ((u32)f2bf(acc[cc][2 * kk + 1]) << 16);
      char* base = lutF + ((size_t)(o >> 4) * KB + (c >> 1)) * 1024;
      const int l0 = (o & 15) + ((c & 1) * 2) * 16;
      *(uint4*)(base + l0 * 16)        = make_uint4(g[0], g[1], g[2], g[3]);
      *(uint4*)(base + (l0 + 16) * 16) = make_uint4(g[4], g[5], g[6], g[7]);
    }
    return;
  }

  // ---- argmin path ----
  const int a = b - 1024;
  const int n0 = (a & 127) * 32;
  const int cg = a >> 7;  // column chunk 0..7 (codebooks cg*16..cg*16+15)
  const int t = tid >> 4;
  const int cl = tid & 15;

  // stage this chunk's centroids: 16 codebooks x 256 floats, pad 260
#pragma unroll
  for (int j2 = 0; j2 < 4; ++j2) {
    const int fi = tid + 256 * j2;
    const int row = fi >> 6;
    const int col = (fi & 63) * 4;
    *(float4*)(cs + row * 260 + col) =
        *(const float4*)(cents + ((size_t)(cg * 16 + row)) * 256 + col);
  }

  // 2 tokens/thread, x subvectors straight to registers (64B contig/thread)
  float xr[2][16];
#pragma unroll
  for (int s = 0; s < 2; ++s)
#pragma unroll
    for (int qq = 0; qq < 4; ++qq) {
      float4 tv = *(const float4*)(x + (size_t)(n0 + t + 16 * s) * IN_DIM +
                                   cg * 256 + cl * 16 + qq * 4);
      xr[s][qq * 4 + 0] = tv.x; xr[s][qq * 4 + 1] = tv.y;
      xr[s][qq * 4 + 2] = tv.z; xr[s][qq * 4 + 3] = tv.w;
    }
  __syncthreads();

  const float* cb = cs + cl * 260;
  int bk0 = 0, bk1 = 0;
  float bd0 = 1e30f, bd1 = 1e30f;
#pragma unroll
  for (int k = 0; k < 16; ++k) {
    float d0 = 0.f, d1 = 0.f;
#pragma unroll
    for (int qq = 0; qq < 4; ++qq) {
      float4 cv = *(const float4*)(cb + k * 16 + qq * 4);
      d0 = fmaxf(d0, fabsf(xr[0][qq * 4 + 0] - cv.x));
      d0 = fmaxf(d0, fabsf(xr[0][qq * 4 + 1] - cv.y));
      d0 = fmaxf(d0, fabsf(xr[0][qq * 4 + 2] - cv.z));
      d0 = fmaxf(d0, fabsf(xr[0][qq * 4 + 3] - cv.w));
      d1 = fmaxf(d1, fabsf(xr[1][qq * 4 + 0] - cv.x));
      d1 = fmaxf(d1, fabsf(xr[1][qq * 4 + 1] - cv.y));
      d1 = fmaxf(d1, fabsf(xr[1][qq * 4 + 2] - cv.z));
      d1 = fmaxf(d1, fabsf(xr[1][qq * 4 + 3] - cv.w));
    }
    if (d0 < bd0) { bd0 = d0; bk0 = k; }
    if (d1 < bd1) { bd1 = d1; bk1 = k; }
  }
  idx[(size_t)(n0 + t) * NCB + cg * 16 + cl] = (unsigned char)bk0;
  idx[(size_t)(n0 + t + 16) * NCB + cg * 16 + cl] = (unsigned char)bk1;
}

// ---------------------------------------------------------------------------
// k_gemm v3: barrier-free one-hot GEMM, wave-tile 32m x 128n.
// Issue-budget fix: per K=32 k-block a wave now does 2 one-hot builds (~10
// VALU each, was 4x12) + 8 B-loads (1-cyc issue) + 16 MFMA, so the MFMA pipe
// (77.6 cyc/k-block) dominates the issue stream instead of VALU.
// One-hot build (layout identical to the R1-passing kernel):
//   lane l: m=l&15 (row in 16-tile), h=l>>4, hb=h>>1 (codebook of pair),
//   par8=(h&1)*8 (centroid half). Pre-XOR idx bytes with 0x08 when par8=8,
//   then uu = nibble; frag = 0x3F80 << 16*uu within 128 bits:
//   dbl = 0x3F80 << ((uu<<4)&63); lo = uu<4 ? dbl : 0; hi = 4<=uu<8 ? dbl:0.
// Block 128m x 128n, 4 waves stacked in m; all waves share the same B bytes
// (L1 hits). XCD swizzle: 1024 blocks = 8 x 128, each XCD owns 4 n-slabs
// (2MB of lutF < 4MB L2).
// ---------------------------------------------------------------------------
__global__ __launch_bounds__(256) void k_gemm(
    const unsigned char* __restrict__ idx,  // [N_TOK][NCB] u8
    const char* __restrict__ Bf,            // fragment-ordered LUT
    const float* __restrict__ bias,
    float* __restrict__ out) {
  __shared__ unsigned char sIdx[128 * 144];  // 18KB, 16B-aligned rows
  const int tid = threadIdx.x;
  const int wave = tid >> 6;
  const int lane = tid & 63;

  // bijective XCD swizzle over grid (32,32)
  const int lin = blockIdx.x + (int)(gridDim.x * blockIdx.y);
  const int slot = lin >> 3;
  const int bx = slot & 31;
  const int by = ((lin & 7) << 2) | (slot >> 5);
  const int m0 = bx * 128;
  const int n0 = by * 128;
  const int wm = wave * 32;

  // ---- stage sIdx (16KB payload, coalesced) ----
#pragma unroll
  for (int j = 0; j < 4; ++j) {
    const int u = tid + 256 * j;
    const int row = u >> 3;
    const int col = (u & 7) * 16;
    *(uint4*)(sIdx + row * 144 + col) =
        *(const uint4*)(idx + (size_t)(m0 + row) * NCB + col);
  }

  // lane constants for the register one-hot build
  const int h = lane >> 4;
  const u32 sh_e = (u32)((h >> 1) * 8);        // even-j nibble shift
  const u32 sh_o = sh_e + 16u;                 // odd-j nibble shift
  const u32 pxor = (h & 1) ? 0x08080808u : 0u; // par8 pre-xor
  const unsigned char* rb0 = sIdx + (wm + (lane & 15)) * 144;
  const unsigned char* rb1 = rb0 + 16 * 144;

  // 8 rolling B offsets (32-bit, SGPR-base addressing); +8192 per q-chunk
  u32 bo[8];
#pragma unroll
  for (int jj = 0; jj < 8; ++jj)
    bo[jj] = (u32)(((n0 >> 4) + jj) * (KB * 1024)) + (u32)lane * 16u;

  __syncthreads();  // sIdx visible -- the ONLY barrier in this kernel

  uint4 Bc[8];
#pragma unroll
  for (int jj = 0; jj < 8; ++jj) Bc[jj] = *(const uint4*)(Bf + bo[jj]);

  f32x4 acc[2][8] = {};

  for (int q = 0; q < 8; ++q) {
    // idx chunk: 16 codebooks (8 k-blocks); broadcast LDS reads, pre-XOR'd
    uint4 c0 = *(const uint4*)(rb0 + q * 16);
    uint4 c1 = *(const uint4*)(rb1 + q * 16);
    c0.x ^= pxor; c0.y ^= pxor; c0.z ^= pxor; c0.w ^= pxor;
    c1.x ^= pxor; c1.y ^= pxor; c1.z ^= pxor; c1.w ^= pxor;

#pragma unroll
    for (int j = 0; j < 8; ++j) {
      // prefetch next k-block's B (q=7,j=7 over-reads 1KB into the idx
      // region: allocated, values dead)
      uint4 Bn[8];
#pragma unroll
      for (int jj = 0; jj < 8; ++jj)
        Bn[jj] = *(const uint4*)(Bf + (bo[jj] + (u32)((j + 1) * 1024)));

      // build 2 one-hot A fragments in registers (~10 VALU each)
      const u32 w0 = ((j >> 1) == 0 ? c0.x : (j >> 1) == 1 ? c0.y
                     : (j >> 1) == 2 ? c0.z : c0.w);
      const u32 w1 = ((j >> 1) == 0 ? c1.x : (j >> 1) == 1 ? c1.y
                     : (j >> 1) == 2 ? c1.z : c1.w);
      const u32 sh = (j & 1) ? sh_o : sh_e;
      const u32 uu0 = (w0 >> sh) & 15u;
      const u32 uu1 = (w1 >> sh) & 15u;
      const u64 dbl0 = 0x3F80ull << ((uu0 << 4) & 63u);
      const u64 dbl1 = 0x3F80ull << ((uu1 << 4) & 63u);
      const u64 lo0 = (uu0 < 4u) ? dbl0 : 0ull;
      const u64 hi0 = (uu0 >= 4u && uu0 < 8u) ? dbl0 : 0ull;
      const u64 lo1 = (uu1 < 4u) ? dbl1 : 0ull;
      const u64 hi1 = (uu1 >= 4u && uu1 < 8u) ? dbl1 : 0ull;
      uint4 f0, f1;
      f0.x = (u32)lo0; f0.y = (u32)(lo0 >> 32);
      f0.z = (u32)hi0; f0.w = (u32)(hi0 >> 32);
      f1.x = (u32)lo1; f1.y = (u32)(lo1 >> 32);
      f1.z = (u32)hi1; f1.w = (u32)(hi1 >> 32);
      const bf16x8 af0 = *(const bf16x8*)&f0;
      const bf16x8 af1 = *(const bf16x8*)&f1;

#pragma unroll
      for (int jj = 0; jj < 8; ++jj) {
        acc[0][jj] = __builtin_amdgcn_mfma_f32_16x16x32_bf16(
            af0, *(const bf16x8*)&Bc[jj], acc[0][jj], 0, 0, 0);
        acc[1][jj] = __builtin_amdgcn_mfma_f32_16x16x32_bf16(
            af1, *(const bf16x8*)&Bc[jj], acc[1][jj], 0, 0, 0);
      }

#pragma unroll
      for (int jj = 0; jj < 8; ++jj) Bc[jj] = Bn[jj];  // SSA-renamed
    }
#pragma unroll
    for (int jj = 0; jj < 8; ++jj) bo[jj] += 8192u;
  }

  // epilogue: D layout col=lane&15, row=(lane>>4)*4+r  [m89-verified]
  const int col = lane & 15;
  const int rq = (lane >> 4) * 4;
  float bj[8];
#pragma unroll
  for (int jj = 0; jj < 8; ++jj) bj[jj] = bias[n0 + jj * 16 + col];
#pragma unroll
  for (int i = 0; i < 2; ++i) {
    const int gm = m0 + wm + i * 16 + rq;
#pragma unroll
    for (int jj = 0; jj < 8; ++jj) {
      float* op = out + (size_t)gm * OUT_DIM + n0 + jj * 16 + col;
#pragma unroll
      for (int r = 0; r < 4; ++r) op[(size_t)r * OUT_DIM] = acc[i][jj][r] + bj[jj];
    }
  }
}

// ---------------------------------------------------------------------------
extern "C" void kernel_launch(void* const* d_in, const int* in_sizes, int n_in,
                              void* d_out, int out_size, void* d_ws, size_t ws_size,
                              hipStream_t stream) {
  (void)in_sizes; (void)n_in; (void)out_size; (void)ws_size;
  const float* x      = (const float*)d_in[0];
  const float* weight = (const float*)d_in[1];
  const float* cents  = (const float*)d_in[2];
  const float* bias   = (const float*)d_in[3];
  // d_in[4] = vec_len (16), hardcoded

  char* lutF = (char*)d_ws;                                              // 16.8MB
  unsigned char* idx = (unsigned char*)d_ws + (size_t)OUT_DIM * CK * 2;  // 512KB
  float* out = (float*)d_out;

  k_prep<<<dim3(2048), 256, 0, stream>>>(x, weight, cents, idx, lutF);
  k_gemm<<<dim3(32, 32), 256, 0, stream>>>(idx, lutF, bias, out);
}